// Round 12
// baseline (384.030 us; speedup 1.0000x reference)
//
#include <hip/hip_runtime.h>
#include <hip/hip_bf16.h>

#define NROWS 8192
#define NITER 10

typedef __attribute__((ext_vector_type(8))) short bf16x8;
typedef __attribute__((ext_vector_type(8))) unsigned short u16x8;
typedef __attribute__((ext_vector_type(16))) float f32x16;

__device__ __forceinline__ float bf2f(unsigned short u) {
  union { float f; unsigned int i; } c; c.i = ((unsigned int)u) << 16; return c.f;
}
__device__ __forceinline__ unsigned short f2bf(float f) {
  unsigned int x = __float_as_uint(f);
  unsigned int r = (x + 0x7FFFu + ((x >> 16) & 1u)) >> 16;
  return (unsigned short)r;
}

// tril inversion, 128-wide grid (64x64 tiles) for ppbuild
#define TRIS(b) ((b) * (257 - (b)) / 2)
__device__ __forceinline__ void tril_decode(int L, int& bi, int& bj) {
  int b = (int)((257.0f - sqrtf((float)(66049 - 8 * L))) * 0.5f);
  if (b > 127) b = 127;
  if (b < 0) b = 0;
  while (b < 127 && TRIS(b + 1) <= L) ++b;
  while (b > 0 && TRIS(b) > L) --b;
  bi = b;
  bj = b + (L - TRIS(b));
}

// tril inversion, 64-wide grid (128x128 tiles) for ppmv
#define TRIS64(b) ((b) * (129 - (b)) / 2)
__device__ __forceinline__ void tril64_decode(int L, int& bi, int& bj) {
  int b = (int)((129.0f - sqrtf((float)(16641 - 8 * L))) * 0.5f);
  if (b > 63) b = 63;
  if (b < 0) b = 0;
  while (b < 63 && TRIS64(b + 1) <= L) ++b;
  while (b > 0 && TRIS64(b) > L) --b;
  bi = b;
  bj = b + (L - TRIS64(b));
}

// one kernel casting x, W1, W2 to bf16 (8 elems/thread)
__global__ __launch_bounds__(256) void cast3(const float* __restrict__ x,
                                             const float* __restrict__ W1,
                                             const float* __restrict__ W2,
                                             unsigned short* __restrict__ xb,
                                             unsigned short* __restrict__ w1b,
                                             unsigned short* __restrict__ w2b) {
  int idx = blockIdx.x * 256 + threadIdx.x;
  const float* src; unsigned short* dst; int l;
  if (idx < 131072) { src = x; dst = xb; l = idx; }
  else if (idx < 139264) { src = W1; dst = w1b; l = idx - 131072; }
  else if (idx < 155648) { src = W2; dst = w2b; l = idx - 139264; }
  else return;
  const float4* p = (const float4*)src + (size_t)l * 2;
  float4 a = p[0], b = p[1];
  u16x8 o;
  o[0] = f2bf(a.x); o[1] = f2bf(a.y); o[2] = f2bf(a.z); o[3] = f2bf(a.w);
  o[4] = f2bf(b.x); o[5] = f2bf(b.y); o[6] = f2bf(b.z); o[7] = f2bf(b.w);
  *(u16x8*)(dst + (size_t)l * 8) = o;
}

// C[M,NN] = A[M,K] @ B[NN,K]^T (bf16 in, bf16 out) + fused per-column
// partial BN stats (sum, sumsq) from the fp32 accumulators.
__global__ __launch_bounds__(256) void gemm_bt_mfma_stats(
    const unsigned short* __restrict__ A, const unsigned short* __restrict__ B,
    unsigned short* __restrict__ Cb, float* __restrict__ pS, float* __restrict__ pQ,
    int NN, int K) {
  __shared__ __align__(16) unsigned short Asw[4096];
  __shared__ __align__(16) unsigned short Bsw[4096];
  __shared__ float Sarr[4][64], Qarr[4][64];
  const int i0 = blockIdx.x * 64, j0 = blockIdx.y * 64;
  const int t = threadIdx.x;
  const int lane = t & 63;
  const int wv = t >> 6;
  const int wi = wv >> 1, wj = wv & 1;
  const int khalf = lane >> 5;

  f32x16 acc;
#pragma unroll
  for (int r = 0; r < 16; ++r) acc[r] = 0.f;

  const int lrow = t >> 2;
  const int lgp = (t & 3) * 2;
  const int arow = wi * 32 + (lane & 31);
  const int brow = wj * 32 + (lane & 31);
  const int nc = K >> 6;
#pragma unroll 1
  for (int c = 0; c < nc; ++c) {
    const unsigned short* sa = A + (size_t)(i0 + lrow) * K + c * 64 + lgp * 8;
    const unsigned short* sb = B + (size_t)(j0 + lrow) * K + c * 64 + lgp * 8;
    u16x8 va0 = *(const u16x8*)(sa);
    u16x8 va1 = *(const u16x8*)(sa + 8);
    u16x8 vb0 = *(const u16x8*)(sb);
    u16x8 vb1 = *(const u16x8*)(sb + 8);
    __syncthreads();
    int s0 = (lgp ^ (lrow & 7)) * 8;
    int s1 = ((lgp + 1) ^ (lrow & 7)) * 8;
    *(u16x8*)&Asw[lrow * 64 + s0] = va0;
    *(u16x8*)&Asw[lrow * 64 + s1] = va1;
    *(u16x8*)&Bsw[lrow * 64 + s0] = vb0;
    *(u16x8*)&Bsw[lrow * 64 + s1] = vb1;
    __syncthreads();
#pragma unroll
    for (int s = 0; s < 4; ++s) {
      int slot = s * 2 + khalf;
      bf16x8 a = *(const bf16x8*)&Asw[arow * 64 + ((slot ^ (arow & 7)) * 8)];
      bf16x8 b = *(const bf16x8*)&Bsw[brow * 64 + ((slot ^ (brow & 7)) * 8)];
      acc = __builtin_amdgcn_mfma_f32_32x32x16_bf16(a, b, acc, 0, 0, 0);
    }
  }
  // epilogue: bf16 store + per-lane column stats (16 rows of column coll)
  float s = 0.f, q = 0.f;
#pragma unroll
  for (int r = 0; r < 16; ++r) {
    int rowl = (r & 3) + 8 * (r >> 2) + 4 * khalf;
    int coll = lane & 31;
    float v = acc[r];
    s += v; q += v * v;
    Cb[(size_t)(i0 + wi * 32 + rowl) * NN + j0 + wj * 32 + coll] = f2bf(v);
  }
  Sarr[wv][lane] = s;
  Qarr[wv][lane] = q;
  __syncthreads();
  if (t < 64) {  // column c of block: fold 4 deterministic contributions
    int wjc = t >> 5, coll = t & 31;
    float st = (Sarr[wjc][coll] + Sarr[wjc][coll + 32]) +
               (Sarr[wjc + 2][coll] + Sarr[wjc + 2][coll + 32]);
    float qt = (Qarr[wjc][coll] + Qarr[wjc][coll + 32]) +
               (Qarr[wjc + 2][coll] + Qarr[wjc + 2][coll + 32]);
    pS[(size_t)blockIdx.x * NN + j0 + t] = st;
    pQ[(size_t)blockIdx.x * NN + j0 + t] = qt;
  }
}

// fold 128 row-block partial stats -> per-column scale/shift
__global__ void bn_finalize(const float* __restrict__ pS, const float* __restrict__ pQ,
                            const float* __restrict__ g, const float* __restrict__ be,
                            float2* __restrict__ ab, int C) {
  int c = blockIdx.x * 256 + threadIdx.x;
  if (c >= C) return;
  float s = 0.f, q = 0.f;
  for (int r = 0; r < 128; ++r) { s += pS[(size_t)r * C + c]; q += pQ[(size_t)r * C + c]; }
  const float invM = 1.f / 8192.f;
  float mu = s * invM;
  float var = q * invM - mu * mu;
  float rstd = rsqrtf(var + 1e-5f);
  float a = g[c] * rstd;
  ab[c] = make_float2(a, be[c] - mu * a);
}

// hb = leaky_relu(a*hraw + b), bf16 -> bf16, 8 elems/thread
__global__ __launch_bounds__(256) void bn_apply(const unsigned short* __restrict__ hraw,
                                                const float2* __restrict__ ab,
                                                unsigned short* __restrict__ hb,
                                                int Cmask) {
  size_t idx = (size_t)blockIdx.x * 256 + threadIdx.x;
  u16x8 v = *(const u16x8*)(hraw + idx * 8);
  int cb = (int)((idx * 8) & (size_t)Cmask);
  u16x8 o;
#pragma unroll
  for (int k = 0; k < 8; ++k) {
    float2 a = ab[cb + k];
    float r = a.x * bf2f(v[k]) + a.y;
    r = r >= 0.f ? r : 0.01f * r;
    o[k] = f2bf(r);
  }
  *(u16x8*)(hb + idx * 8) = o;
}

// fused: feats-BN + leaky + row norm + fc logit; writes fnorm bf16, unary, coef0
__global__ __launch_bounds__(256) void bn_rowfn(const unsigned short* __restrict__ fraw,
                                                const float2* __restrict__ ab,
                                                const float* __restrict__ fcw,
                                                const float* __restrict__ fcb,
                                                unsigned short* __restrict__ fnorm,
                                                float* __restrict__ unary,
                                                float* __restrict__ coef0) {
  const int lane = threadIdx.x & 63;
  const int row = blockIdx.x * 4 + (threadIdx.x >> 6);
  ushort4 v4 = *(const ushort4*)(fraw + (size_t)row * 256 + lane * 4);
  float4 w = *(const float4*)(fcw + lane * 4);
  int c = lane * 4;
  float2 a0 = ab[c], a1 = ab[c + 1], a2 = ab[c + 2], a3 = ab[c + 3];
  float f0 = a0.x * bf2f(v4.x) + a0.y; f0 = f0 >= 0.f ? f0 : 0.01f * f0;
  float f1 = a1.x * bf2f(v4.y) + a1.y; f1 = f1 >= 0.f ? f1 : 0.01f * f1;
  float f2 = a2.x * bf2f(v4.z) + a2.y; f2 = f2 >= 0.f ? f2 : 0.01f * f2;
  float f3 = a3.x * bf2f(v4.w) + a3.y; f3 = f3 >= 0.f ? f3 : 0.01f * f3;
  float ssq = f0 * f0 + f1 * f1 + f2 * f2 + f3 * f3;
  float dot = f0 * w.x + f1 * w.y + f2 * w.z + f3 * w.w;
#pragma unroll
  for (int o = 32; o; o >>= 1) { ssq += __shfl_xor(ssq, o); dot += __shfl_xor(dot, o); }
  float rfn = rsqrtf(ssq);
  *(ushort4*)(fnorm + (size_t)row * 256 + lane * 4) =
      make_ushort4(f2bf(f0 * rfn), f2bf(f1 * rfn), f2bf(f2 * rfn), f2bf(f3 * rfn));
  if (lane == 0) {
    float lg = dot + fcb[0];
    unary[row] = lg;
    coef0[row] = 1.f - 2.f / (1.f + __expf(-lg));
  }
}

// PP[i,j] = (fnorm_i . fnorm_j) * 0.5*(W[i,j]+W[j,i]); upper-triangle only.
__global__ __launch_bounds__(256) void ppbuild_sym(const unsigned short* __restrict__ fnorm,
                                                   const float* __restrict__ W,
                                                   unsigned short* __restrict__ PP) {
  int bi, bj;
  tril_decode(blockIdx.x, bi, bj);
  const int i0 = bi * 64, j0 = bj * 64;

  __shared__ __align__(16) unsigned char shm[18944];
  unsigned short* Asw = (unsigned short*)shm;
  unsigned short* Bsw = (unsigned short*)shm + 4736;
  float (*Wt)[68] = (float(*)[68])shm;
  unsigned short* OutD = (unsigned short*)shm;

  const int t = threadIdx.x;
  const int lane = t & 63;
  const int wv = t >> 6;
  const int wi = wv >> 1, wj = wv & 1;
  const int khalf = lane >> 5;

  f32x16 acc;
#pragma unroll
  for (int r = 0; r < 16; ++r) acc[r] = 0.f;

  const int lrow = t >> 2;
  const int lgp = (t & 3) * 2;
  const int arow = wi * 32 + (lane & 31);
  const int brow = wj * 32 + (lane & 31);
#pragma unroll 1
  for (int c = 0; c < 4; ++c) {
    const unsigned short* sa = fnorm + (size_t)(i0 + lrow) * 256 + c * 64 + lgp * 8;
    const unsigned short* sb = fnorm + (size_t)(j0 + lrow) * 256 + c * 64 + lgp * 8;
    u16x8 va0 = *(const u16x8*)(sa);
    u16x8 va1 = *(const u16x8*)(sa + 8);
    u16x8 vb0 = *(const u16x8*)(sb);
    u16x8 vb1 = *(const u16x8*)(sb + 8);
    __syncthreads();
    int s0 = (lgp ^ (lrow & 7)) * 8;
    int s1 = ((lgp + 1) ^ (lrow & 7)) * 8;
    *(u16x8*)&Asw[lrow * 64 + s0] = va0;
    *(u16x8*)&Asw[lrow * 64 + s1] = va1;
    *(u16x8*)&Bsw[lrow * 64 + s0] = vb0;
    *(u16x8*)&Bsw[lrow * 64 + s1] = vb1;
    __syncthreads();
#pragma unroll
    for (int s = 0; s < 4; ++s) {
      int slot = s * 2 + khalf;
      bf16x8 a = *(const bf16x8*)&Asw[arow * 64 + ((slot ^ (arow & 7)) * 8)];
      bf16x8 b = *(const bf16x8*)&Bsw[brow * 64 + ((slot ^ (brow & 7)) * 8)];
      acc = __builtin_amdgcn_mfma_f32_32x32x16_bf16(a, b, acc, 0, 0, 0);
    }
  }

  __syncthreads();
  {
    const int j = t >> 2, cb = (t & 3) * 16;
    const float* src = W + (size_t)(j0 + j) * NROWS + i0 + cb;
#pragma unroll
    for (int q = 0; q < 4; ++q) {
      float4 v = *(const float4*)(src + q * 4);
      Wt[j][cb + q * 4 + 0] = v.x; Wt[j][cb + q * 4 + 1] = v.y;
      Wt[j][cb + q * 4 + 2] = v.z; Wt[j][cb + q * 4 + 3] = v.w;
    }
  }
  __syncthreads();
  unsigned short pb[16];
#pragma unroll
  for (int r = 0; r < 16; ++r) {
    int rowl = (r & 3) + 8 * (r >> 2) + 4 * khalf;
    int coll = lane & 31;
    int il = wi * 32 + rowl, jl = wj * 32 + coll;
    float wd = W[(size_t)(i0 + il) * NROWS + (j0 + jl)];
    float ws = 0.5f * (wd + Wt[jl][il]);
    pb[r] = f2bf(acc[r] * ws);
  }
  __syncthreads();
#pragma unroll
  for (int r = 0; r < 16; ++r) {
    int rowl = (r & 3) + 8 * (r >> 2) + 4 * khalf;
    int coll = lane & 31;
    OutD[(wi * 32 + rowl) * 74 + wj * 32 + coll] = pb[r];
  }
  __syncthreads();
  const int row = t >> 3;
  const int seg = t & 7;
#pragma unroll
  for (int q = 0; q < 2; ++q) {
    int rr = row + q * 32;
    const unsigned int* pd = (const unsigned int*)(OutD + rr * 74 + seg * 8);
    union { u16x8 v; unsigned int u[4]; } dd;
#pragma unroll
    for (int k = 0; k < 4; ++k) dd.u[k] = pd[k];
    *(u16x8*)(PP + (size_t)(i0 + rr) * NROWS + j0 + seg * 8) = dd.v;
  }
}

// Fused symmetric matvec iteration: per block, recompute coef for its 256
// rows from pEprev (bit-identical fold -> deterministic), then 128x128
// symmetric tile partials into pEout. pE is double-buffered by the caller.
__global__ __launch_bounds__(256) void ppmv_fused(const unsigned short* __restrict__ PP,
                                                  const float* __restrict__ unary,
                                                  const float* __restrict__ pEprev,
                                                  const float* __restrict__ coef0,
                                                  float* __restrict__ pEout) {
  int bi, bj;
  tril64_decode(blockIdx.x, bi, bj);
  const int i0 = bi * 128, j0 = bj * 128;
  const int t = threadIdx.x;

  __shared__ __align__(16) unsigned short tile[128][132];  // 33792 B
  __shared__ float cj[128], ci[128];
  __shared__ float Tw[8][128];
  __shared__ float Dred[128];

  // issue PP tile loads into registers first (HBM/L3 latency overlaps fold)
  const int r = t >> 1, h = (t & 1) * 64;
  u16x8 tv[8];
  {
    const unsigned short* src = PP + (size_t)(i0 + r) * NROWS + j0 + h;
#pragma unroll
    for (int q = 0; q < 8; ++q) tv[q] = *(const u16x8*)(src + q * 8);
  }
  // coef for this thread's row (t<128 -> cj[j0+t], else ci[i0+t-128])
  {
    int myrow = (t < 128) ? (j0 + t) : (i0 + (t - 128));
    float c;
    if (pEprev) {
      float a = 0.f;
#pragma unroll 8
      for (int s = 0; s < 64; ++s) a += pEprev[(size_t)s * NROWS + myrow];
      float lg = unary[myrow] + a;
      c = 1.f - 2.f / (1.f + __expf(-lg));
    } else {
      c = coef0[myrow];
    }
    if (t < 128) cj[t] = c;
    else ci[t - 128] = c;
  }
#pragma unroll
  for (int q = 0; q < 8; ++q) *(u16x8*)&tile[r][h + q * 8] = tv[q];
  __syncthreads();
  // row sums: thread owns half a row (64 cols), vectorized LDS reads
  {
    float a = 0.f;
#pragma unroll
    for (int q = 0; q < 8; ++q) {
      u16x8 v = *(const u16x8*)&tile[r][h + q * 8];
      float4 c0 = *(const float4*)&cj[h + q * 8];
      float4 c1 = *(const float4*)&cj[h + q * 8 + 4];
      a += bf2f(v[0]) * c0.x + bf2f(v[1]) * c0.y + bf2f(v[2]) * c0.z + bf2f(v[3]) * c0.w;
      a += bf2f(v[4]) * c1.x + bf2f(v[5]) * c1.y + bf2f(v[6]) * c1.z + bf2f(v[7]) * c1.w;
    }
    a += __shfl_xor(a, 1);
    if ((t & 1) == 0) Dred[r] = a;
  }
  // col sums: thread owns 4 cols x 16 rows (ushort4 LDS reads), 8 row-groups
  {
    const int c4 = (t & 31) * 4, rg = t >> 5;
    float a0 = 0.f, a1 = 0.f, a2 = 0.f, a3 = 0.f;
#pragma unroll
    for (int k = 0; k < 16; ++k) {
      int row = rg * 16 + k;
      ushort4 v = *(const ushort4*)&tile[row][c4];
      float s = ci[row];
      a0 += bf2f(v.x) * s; a1 += bf2f(v.y) * s;
      a2 += bf2f(v.z) * s; a3 += bf2f(v.w) * s;
    }
    Tw[rg][c4] = a0; Tw[rg][c4 + 1] = a1;
    Tw[rg][c4 + 2] = a2; Tw[rg][c4 + 3] = a3;
  }
  __syncthreads();
  if (t < 128) {
    pEout[(size_t)bj * NROWS + i0 + t] = Dred[t];
    if (bi != bj) {
      float s = ((Tw[0][t] + Tw[1][t]) + (Tw[2][t] + Tw[3][t])) +
                ((Tw[4][t] + Tw[5][t]) + (Tw[6][t] + Tw[7][t]));
      pEout[(size_t)bi * NROWS + j0 + t] = s;
    }
  }
}

// final: lg = unary + fold(pE)  -> out
__global__ __launch_bounds__(256) void final_fold(const float* __restrict__ pE,
                                                  const float* __restrict__ unary,
                                                  float* __restrict__ out) {
  int row = blockIdx.x * 256 + threadIdx.x;
  float acc = 0.f;
#pragma unroll 8
  for (int s = 0; s < 64; ++s) acc += pE[(size_t)s * NROWS + row];
  out[row] = unary[row] + acc;
}

extern "C" void kernel_launch(void* const* d_in, const int* in_sizes, int n_in,
                              void* d_out, int out_size, void* d_ws, size_t ws_size,
                              hipStream_t stream) {
  const float* x   = (const float*)d_in[0];
  const float* W   = (const float*)d_in[1];
  const float* W1  = (const float*)d_in[2];
  const float* g1  = (const float*)d_in[4];
  const float* be1 = (const float*)d_in[5];
  const float* W2  = (const float*)d_in[6];
  const float* g2  = (const float*)d_in[8];
  const float* be2 = (const float*)d_in[9];
  const float* fcw = (const float*)d_in[10];
  const float* fcb = (const float*)d_in[11];
  float* out = (float*)d_out;

  char* ws = (char*)d_ws;
  unsigned short* hraw = (unsigned short*)(ws + 0);          // 8 MB (pE aliases later)
  float* pEA   = (float*)(ws + 0);                           // 2 MB (after hraw dead)
  float* pEB   = (float*)(ws + 2097152);                     // 2 MB
  unsigned short* fraw = (unsigned short*)(ws + 8388608);    // 4 MB
  float* pS1   = (float*)(ws + 12582912);                    // 256 KB
  float* pQ1   = (float*)(ws + 12845056);                    // 256 KB
  float* pS2   = (float*)(ws + 13107200);                    // 128 KB
  float* pQ2   = (float*)(ws + 13238272);                    // 128 KB
  float2* ab1  = (float2*)(ws + 13369344);                   // 4 KB
  float2* ab2  = (float2*)(ws + 13373440);                   // 2 KB
  unsigned short* fnorm = (unsigned short*)(ws + 13375488);  // 4 MB
  float* unary = (float*)(ws + 17569792);
  float* coefA = (float*)(ws + 17602560);
  unsigned short* hb  = (unsigned short*)(ws + 17668096);    // 8 MB
  unsigned short* xb  = (unsigned short*)(ws + 26056704);    // 2 MB
  unsigned short* w1b = (unsigned short*)(ws + 28153856);    // 128 KB
  unsigned short* w2b = (unsigned short*)(ws + 28284928);    // 256 KB
  unsigned short* PP  = (unsigned short*)(ws + 28547072);    // 128 MB
  if (ws_size < (size_t)162764800) return;

  // casts (one kernel)
  cast3<<<608, 256, 0, stream>>>(x, W1, W2, xb, w1b, w2b);
  // layer 1: hraw = x @ W1^T (bf16 out + fused col stats); BN; leaky -> hb
  gemm_bt_mfma_stats<<<dim3(128, 8), 256, 0, stream>>>(xb, w1b, hraw, pS1, pQ1, 512, 128);
  bn_finalize<<<2, 256, 0, stream>>>(pS1, pQ1, g1, be1, ab1, 512);
  bn_apply<<<2048, 256, 0, stream>>>(hraw, ab1, hb, 511);
  // layer 2: fraw = hb @ W2^T (bf16 out + fused col stats); BN+rowfn fused
  gemm_bt_mfma_stats<<<dim3(128, 4), 256, 0, stream>>>(hb, w2b, fraw, pS2, pQ2, 256, 512);
  bn_finalize<<<1, 256, 0, stream>>>(pS2, pQ2, g2, be2, ab2, 256);
  bn_rowfn<<<2048, 256, 0, stream>>>(fraw, ab2, fcw, fcb, fnorm, unary, coefA);
  // PP upper triangle (hraw dead; pEA/pEB alias it)
  ppbuild_sym<<<8256, 256, 0, stream>>>(fnorm, W, PP);
  // 10 fused iterations (coef fold inside the kernel; pE double-buffered;
  // no grid.sync — costs ~125 us/sync on 8-XCD MI355X, measured round 8)
  ppmv_fused<<<2080, 256, 0, stream>>>(PP, unary, nullptr, coefA, pEA);
  float* prev = pEA; float* nxt = pEB;
  for (int it = 1; it < NITER; ++it) {
    ppmv_fused<<<2080, 256, 0, stream>>>(PP, unary, prev, nullptr, nxt);
    float* tmp = prev; prev = nxt; nxt = tmp;
  }
  final_fold<<<32, 256, 0, stream>>>(prev, unary, out);
}

// Round 13
// 337.409 us; speedup vs baseline: 1.1382x; 1.1382x over previous
//
#include <hip/hip_runtime.h>
#include <hip/hip_bf16.h>

#define NROWS 8192
#define NITER 10

typedef __attribute__((ext_vector_type(8))) short bf16x8;
typedef __attribute__((ext_vector_type(8))) unsigned short u16x8;
typedef __attribute__((ext_vector_type(16))) float f32x16;

__device__ __forceinline__ float bf2f(unsigned short u) {
  union { float f; unsigned int i; } c; c.i = ((unsigned int)u) << 16; return c.f;
}
__device__ __forceinline__ unsigned short f2bf(float f) {
  unsigned int x = __float_as_uint(f);
  unsigned int r = (x + 0x7FFFu + ((x >> 16) & 1u)) >> 16;
  return (unsigned short)r;
}

// tril inversion, 128-wide grid (64x64 tiles) for ppbuild
#define TRIS(b) ((b) * (257 - (b)) / 2)
__device__ __forceinline__ void tril_decode(int L, int& bi, int& bj) {
  int b = (int)((257.0f - sqrtf((float)(66049 - 8 * L))) * 0.5f);
  if (b > 127) b = 127;
  if (b < 0) b = 0;
  while (b < 127 && TRIS(b + 1) <= L) ++b;
  while (b > 0 && TRIS(b) > L) --b;
  bi = b;
  bj = b + (L - TRIS(b));
}

// tril inversion, 64-wide grid (128x128 tiles) for ppmv
#define TRIS64(b) ((b) * (129 - (b)) / 2)
__device__ __forceinline__ void tril64_decode(int L, int& bi, int& bj) {
  int b = (int)((129.0f - sqrtf((float)(16641 - 8 * L))) * 0.5f);
  if (b > 63) b = 63;
  if (b < 0) b = 0;
  while (b < 63 && TRIS64(b + 1) <= L) ++b;
  while (b > 0 && TRIS64(b) > L) --b;
  bi = b;
  bj = b + (L - TRIS64(b));
}

// one kernel casting x, W1, W2 to bf16 (8 elems/thread)
__global__ __launch_bounds__(256) void cast3(const float* __restrict__ x,
                                             const float* __restrict__ W1,
                                             const float* __restrict__ W2,
                                             unsigned short* __restrict__ xb,
                                             unsigned short* __restrict__ w1b,
                                             unsigned short* __restrict__ w2b) {
  int idx = blockIdx.x * 256 + threadIdx.x;
  const float* src; unsigned short* dst; int l;
  if (idx < 131072) { src = x; dst = xb; l = idx; }
  else if (idx < 139264) { src = W1; dst = w1b; l = idx - 131072; }
  else if (idx < 155648) { src = W2; dst = w2b; l = idx - 139264; }
  else return;
  const float4* p = (const float4*)src + (size_t)l * 2;
  float4 a = p[0], b = p[1];
  u16x8 o;
  o[0] = f2bf(a.x); o[1] = f2bf(a.y); o[2] = f2bf(a.z); o[3] = f2bf(a.w);
  o[4] = f2bf(b.x); o[5] = f2bf(b.y); o[6] = f2bf(b.z); o[7] = f2bf(b.w);
  *(u16x8*)(dst + (size_t)l * 8) = o;
}

// C[M,NN] = A[M,K] @ B[NN,K]^T (bf16 in, bf16 out) + fused per-column
// partial BN stats (sum, sumsq) from the fp32 accumulators.
__global__ __launch_bounds__(256) void gemm_bt_mfma_stats(
    const unsigned short* __restrict__ A, const unsigned short* __restrict__ B,
    unsigned short* __restrict__ Cb, float* __restrict__ pS, float* __restrict__ pQ,
    int NN, int K) {
  __shared__ __align__(16) unsigned short Asw[4096];
  __shared__ __align__(16) unsigned short Bsw[4096];
  __shared__ float Sarr[4][64], Qarr[4][64];
  const int i0 = blockIdx.x * 64, j0 = blockIdx.y * 64;
  const int t = threadIdx.x;
  const int lane = t & 63;
  const int wv = t >> 6;
  const int wi = wv >> 1, wj = wv & 1;
  const int khalf = lane >> 5;

  f32x16 acc;
#pragma unroll
  for (int r = 0; r < 16; ++r) acc[r] = 0.f;

  const int lrow = t >> 2;
  const int lgp = (t & 3) * 2;
  const int arow = wi * 32 + (lane & 31);
  const int brow = wj * 32 + (lane & 31);
  const int nc = K >> 6;
#pragma unroll 1
  for (int c = 0; c < nc; ++c) {
    const unsigned short* sa = A + (size_t)(i0 + lrow) * K + c * 64 + lgp * 8;
    const unsigned short* sb = B + (size_t)(j0 + lrow) * K + c * 64 + lgp * 8;
    u16x8 va0 = *(const u16x8*)(sa);
    u16x8 va1 = *(const u16x8*)(sa + 8);
    u16x8 vb0 = *(const u16x8*)(sb);
    u16x8 vb1 = *(const u16x8*)(sb + 8);
    __syncthreads();
    int s0 = (lgp ^ (lrow & 7)) * 8;
    int s1 = ((lgp + 1) ^ (lrow & 7)) * 8;
    *(u16x8*)&Asw[lrow * 64 + s0] = va0;
    *(u16x8*)&Asw[lrow * 64 + s1] = va1;
    *(u16x8*)&Bsw[lrow * 64 + s0] = vb0;
    *(u16x8*)&Bsw[lrow * 64 + s1] = vb1;
    __syncthreads();
#pragma unroll
    for (int s = 0; s < 4; ++s) {
      int slot = s * 2 + khalf;
      bf16x8 a = *(const bf16x8*)&Asw[arow * 64 + ((slot ^ (arow & 7)) * 8)];
      bf16x8 b = *(const bf16x8*)&Bsw[brow * 64 + ((slot ^ (brow & 7)) * 8)];
      acc = __builtin_amdgcn_mfma_f32_32x32x16_bf16(a, b, acc, 0, 0, 0);
    }
  }
  // epilogue: bf16 store + per-lane column stats (16 rows of column coll)
  float s = 0.f, q = 0.f;
#pragma unroll
  for (int r = 0; r < 16; ++r) {
    int rowl = (r & 3) + 8 * (r >> 2) + 4 * khalf;
    int coll = lane & 31;
    float v = acc[r];
    s += v; q += v * v;
    Cb[(size_t)(i0 + wi * 32 + rowl) * NN + j0 + wj * 32 + coll] = f2bf(v);
  }
  Sarr[wv][lane] = s;
  Qarr[wv][lane] = q;
  __syncthreads();
  if (t < 64) {  // column c of block: fold 4 deterministic contributions
    int wjc = t >> 5, coll = t & 31;
    float st = (Sarr[wjc][coll] + Sarr[wjc][coll + 32]) +
               (Sarr[wjc + 2][coll] + Sarr[wjc + 2][coll + 32]);
    float qt = (Qarr[wjc][coll] + Qarr[wjc][coll + 32]) +
               (Qarr[wjc + 2][coll] + Qarr[wjc + 2][coll + 32]);
    pS[(size_t)blockIdx.x * NN + j0 + t] = st;
    pQ[(size_t)blockIdx.x * NN + j0 + t] = qt;
  }
}

// fold 128 row-block partial stats -> per-column scale/shift
__global__ void bn_finalize(const float* __restrict__ pS, const float* __restrict__ pQ,
                            const float* __restrict__ g, const float* __restrict__ be,
                            float2* __restrict__ ab, int C) {
  int c = blockIdx.x * 256 + threadIdx.x;
  if (c >= C) return;
  float s = 0.f, q = 0.f;
  for (int r = 0; r < 128; ++r) { s += pS[(size_t)r * C + c]; q += pQ[(size_t)r * C + c]; }
  const float invM = 1.f / 8192.f;
  float mu = s * invM;
  float var = q * invM - mu * mu;
  float rstd = rsqrtf(var + 1e-5f);
  float a = g[c] * rstd;
  ab[c] = make_float2(a, be[c] - mu * a);
}

// hb = leaky_relu(a*hraw + b), bf16 -> bf16, 8 elems/thread
__global__ __launch_bounds__(256) void bn_apply(const unsigned short* __restrict__ hraw,
                                                const float2* __restrict__ ab,
                                                unsigned short* __restrict__ hb,
                                                int Cmask) {
  size_t idx = (size_t)blockIdx.x * 256 + threadIdx.x;
  u16x8 v = *(const u16x8*)(hraw + idx * 8);
  int cb = (int)((idx * 8) & (size_t)Cmask);
  u16x8 o;
#pragma unroll
  for (int k = 0; k < 8; ++k) {
    float2 a = ab[cb + k];
    float r = a.x * bf2f(v[k]) + a.y;
    r = r >= 0.f ? r : 0.01f * r;
    o[k] = f2bf(r);
  }
  *(u16x8*)(hb + idx * 8) = o;
}

// fused: feats-BN + leaky + row norm + fc logit; writes fnorm bf16, unary, coef0
__global__ __launch_bounds__(256) void bn_rowfn(const unsigned short* __restrict__ fraw,
                                                const float2* __restrict__ ab,
                                                const float* __restrict__ fcw,
                                                const float* __restrict__ fcb,
                                                unsigned short* __restrict__ fnorm,
                                                float* __restrict__ unary,
                                                float* __restrict__ coef0) {
  const int lane = threadIdx.x & 63;
  const int row = blockIdx.x * 4 + (threadIdx.x >> 6);
  ushort4 v4 = *(const ushort4*)(fraw + (size_t)row * 256 + lane * 4);
  float4 w = *(const float4*)(fcw + lane * 4);
  int c = lane * 4;
  float2 a0 = ab[c], a1 = ab[c + 1], a2 = ab[c + 2], a3 = ab[c + 3];
  float f0 = a0.x * bf2f(v4.x) + a0.y; f0 = f0 >= 0.f ? f0 : 0.01f * f0;
  float f1 = a1.x * bf2f(v4.y) + a1.y; f1 = f1 >= 0.f ? f1 : 0.01f * f1;
  float f2 = a2.x * bf2f(v4.z) + a2.y; f2 = f2 >= 0.f ? f2 : 0.01f * f2;
  float f3 = a3.x * bf2f(v4.w) + a3.y; f3 = f3 >= 0.f ? f3 : 0.01f * f3;
  float ssq = f0 * f0 + f1 * f1 + f2 * f2 + f3 * f3;
  float dot = f0 * w.x + f1 * w.y + f2 * w.z + f3 * w.w;
#pragma unroll
  for (int o = 32; o; o >>= 1) { ssq += __shfl_xor(ssq, o); dot += __shfl_xor(dot, o); }
  float rfn = rsqrtf(ssq);
  *(ushort4*)(fnorm + (size_t)row * 256 + lane * 4) =
      make_ushort4(f2bf(f0 * rfn), f2bf(f1 * rfn), f2bf(f2 * rfn), f2bf(f3 * rfn));
  if (lane == 0) {
    float lg = dot + fcb[0];
    unary[row] = lg;
    coef0[row] = 1.f - 2.f / (1.f + __expf(-lg));
  }
}

// PP[i,j] = (fnorm_i . fnorm_j) * 0.5*(W[i,j]+W[j,i]); upper-triangle only,
// PLUS fused iteration-1 symmetric matvec partials (coef0) into pE128.
// Slot layout: pE128[bj][i-rows] (D) and pE128[bi][j-rows] (T, bi!=bj):
// every cell written exactly once -> deterministic, no zero-init needed.
__global__ __launch_bounds__(256) void ppbuild_sym(const unsigned short* __restrict__ fnorm,
                                                   const float* __restrict__ W,
                                                   unsigned short* __restrict__ PP,
                                                   const float* __restrict__ coef0,
                                                   float* __restrict__ pE128) {
  int bi, bj;
  tril_decode(blockIdx.x, bi, bj);
  const int i0 = bi * 64, j0 = bj * 64;

  __shared__ __align__(16) unsigned char shm[18944];
  unsigned short* Asw = (unsigned short*)shm;
  unsigned short* Bsw = (unsigned short*)shm + 4736;
  float (*Wt)[68] = (float(*)[68])shm;
  unsigned short* OutD = (unsigned short*)shm;          // [64][74]
  float* cjD = (float*)(shm + 11264);                   // 64
  float* ciD = cjD + 64;                                // 64
  float* TwD = ciD + 64;                                // [4][64]
  float* DrD = TwD + 256;                               // 64

  const int t = threadIdx.x;
  const int lane = t & 63;
  const int wv = t >> 6;
  const int wi = wv >> 1, wj = wv & 1;
  const int khalf = lane >> 5;

  f32x16 acc;
#pragma unroll
  for (int r = 0; r < 16; ++r) acc[r] = 0.f;

  const int lrow = t >> 2;
  const int lgp = (t & 3) * 2;
  const int arow = wi * 32 + (lane & 31);
  const int brow = wj * 32 + (lane & 31);
#pragma unroll 1
  for (int c = 0; c < 4; ++c) {
    const unsigned short* sa = fnorm + (size_t)(i0 + lrow) * 256 + c * 64 + lgp * 8;
    const unsigned short* sb = fnorm + (size_t)(j0 + lrow) * 256 + c * 64 + lgp * 8;
    u16x8 va0 = *(const u16x8*)(sa);
    u16x8 va1 = *(const u16x8*)(sa + 8);
    u16x8 vb0 = *(const u16x8*)(sb);
    u16x8 vb1 = *(const u16x8*)(sb + 8);
    __syncthreads();
    int s0 = (lgp ^ (lrow & 7)) * 8;
    int s1 = ((lgp + 1) ^ (lrow & 7)) * 8;
    *(u16x8*)&Asw[lrow * 64 + s0] = va0;
    *(u16x8*)&Asw[lrow * 64 + s1] = va1;
    *(u16x8*)&Bsw[lrow * 64 + s0] = vb0;
    *(u16x8*)&Bsw[lrow * 64 + s1] = vb1;
    __syncthreads();
#pragma unroll
    for (int s = 0; s < 4; ++s) {
      int slot = s * 2 + khalf;
      bf16x8 a = *(const bf16x8*)&Asw[arow * 64 + ((slot ^ (arow & 7)) * 8)];
      bf16x8 b = *(const bf16x8*)&Bsw[brow * 64 + ((slot ^ (brow & 7)) * 8)];
      acc = __builtin_amdgcn_mfma_f32_32x32x16_bf16(a, b, acc, 0, 0, 0);
    }
  }

  __syncthreads();
  {
    const int j = t >> 2, cb = (t & 3) * 16;
    const float* src = W + (size_t)(j0 + j) * NROWS + i0 + cb;
#pragma unroll
    for (int q = 0; q < 4; ++q) {
      float4 v = *(const float4*)(src + q * 4);
      Wt[j][cb + q * 4 + 0] = v.x; Wt[j][cb + q * 4 + 1] = v.y;
      Wt[j][cb + q * 4 + 2] = v.z; Wt[j][cb + q * 4 + 3] = v.w;
    }
  }
  __syncthreads();
  unsigned short pb[16];
#pragma unroll
  for (int r = 0; r < 16; ++r) {
    int rowl = (r & 3) + 8 * (r >> 2) + 4 * khalf;
    int coll = lane & 31;
    int il = wi * 32 + rowl, jl = wj * 32 + coll;
    float wd = W[(size_t)(i0 + il) * NROWS + (j0 + jl)];
    float ws = 0.5f * (wd + Wt[jl][il]);
    pb[r] = f2bf(acc[r] * ws);
  }
  __syncthreads();
#pragma unroll
  for (int r = 0; r < 16; ++r) {
    int rowl = (r & 3) + 8 * (r >> 2) + 4 * khalf;
    int coll = lane & 31;
    OutD[(wi * 32 + rowl) * 74 + wj * 32 + coll] = pb[r];
  }
  // stage iteration-1 coefs while OutD settles
  if (t < 64) cjD[t] = coef0[j0 + t];
  else if (t < 128) ciD[t - 64] = coef0[i0 + (t - 64)];
  __syncthreads();
  // PP stores (coalesced from OutD)
  {
    const int row = t >> 3;
    const int seg = t & 7;
#pragma unroll
    for (int q = 0; q < 2; ++q) {
      int rr = row + q * 32;
      const unsigned int* pd = (const unsigned int*)(OutD + rr * 74 + seg * 8);
      union { u16x8 v; unsigned int u[4]; } dd;
#pragma unroll
      for (int k = 0; k < 4; ++k) dd.u[k] = pd[k];
      *(u16x8*)(PP + (size_t)(i0 + rr) * NROWS + j0 + seg * 8) = dd.v;
    }
  }
  // fused iteration-1 partials from OutD
  {
    int r = t >> 2, c0 = (t & 3) * 16;
    float a = 0.f;
#pragma unroll
    for (int k = 0; k < 16; ++k) a += bf2f(OutD[r * 74 + c0 + k]) * cjD[c0 + k];
    a += __shfl_xor(a, 1);
    a += __shfl_xor(a, 2);
    if ((t & 3) == 0) DrD[r] = a;
  }
  {
    int c = t & 63, w = t >> 6;
    float a = 0.f;
#pragma unroll
    for (int k = 0; k < 16; ++k) a += bf2f(OutD[(w * 16 + k) * 74 + c]) * ciD[w * 16 + k];
    TwD[w * 64 + c] = a;
  }
  __syncthreads();
  if (t < 64) {
    pE128[(size_t)bj * NROWS + i0 + t] = DrD[t];
    if (bi != bj) {
      float s = (TwD[t] + TwD[64 + t]) + (TwD[128 + t] + TwD[192 + t]);
      pE128[(size_t)bi * NROWS + j0 + t] = s;
    }
  }
}

// symmetric matvec partials, 128x128 tiles over a 64-block triangular grid.
__global__ __launch_bounds__(256) void ppmv_sym(const unsigned short* __restrict__ PP,
                                                const float* __restrict__ coef_in,
                                                float* __restrict__ pE) {
  int bi, bj;
  tril64_decode(blockIdx.x, bi, bj);
  const int i0 = bi * 128, j0 = bj * 128;
  const int t = threadIdx.x;

  __shared__ __align__(16) unsigned short tile[128][132];  // 33792 B
  __shared__ float cj[128], ci[128];
  __shared__ float Tw[8][128];
  __shared__ float Dred[128];

  if (t < 128) cj[t] = coef_in[j0 + t];
  else ci[t - 128] = coef_in[i0 + (t - 128)];
  {
    const int r = t >> 1, h = (t & 1) * 64;
    const unsigned short* src = PP + (size_t)(i0 + r) * NROWS + j0 + h;
#pragma unroll
    for (int q = 0; q < 8; ++q)
      *(u16x8*)&tile[r][h + q * 8] = *(const u16x8*)(src + q * 8);
  }
  __syncthreads();
  // row sums: thread owns half a row (64 cols), vectorized LDS reads
  {
    const int r = t >> 1, h = (t & 1) * 64;
    float a = 0.f;
#pragma unroll
    for (int q = 0; q < 8; ++q) {
      u16x8 v = *(const u16x8*)&tile[r][h + q * 8];
      float4 c0 = *(const float4*)&cj[h + q * 8];
      float4 c1 = *(const float4*)&cj[h + q * 8 + 4];
      a += bf2f(v[0]) * c0.x + bf2f(v[1]) * c0.y + bf2f(v[2]) * c0.z + bf2f(v[3]) * c0.w;
      a += bf2f(v[4]) * c1.x + bf2f(v[5]) * c1.y + bf2f(v[6]) * c1.z + bf2f(v[7]) * c1.w;
    }
    a += __shfl_xor(a, 1);
    if ((t & 1) == 0) Dred[r] = a;
  }
  // col sums: thread owns 4 cols x 16 rows (ushort4 LDS reads), 8 row-groups
  {
    const int c4 = (t & 31) * 4, rg = t >> 5;
    float a0 = 0.f, a1 = 0.f, a2 = 0.f, a3 = 0.f;
#pragma unroll
    for (int k = 0; k < 16; ++k) {
      int row = rg * 16 + k;
      ushort4 v = *(const ushort4*)&tile[row][c4];
      float s = ci[row];
      a0 += bf2f(v.x) * s; a1 += bf2f(v.y) * s;
      a2 += bf2f(v.z) * s; a3 += bf2f(v.w) * s;
    }
    Tw[rg][c4] = a0; Tw[rg][c4 + 1] = a1;
    Tw[rg][c4 + 2] = a2; Tw[rg][c4 + 3] = a3;
  }
  __syncthreads();
  if (t < 128) {
    pE[(size_t)bj * NROWS + i0 + t] = Dred[t];
    if (bi != bj) {
      float s = ((Tw[0][t] + Tw[1][t]) + (Tw[2][t] + Tw[3][t])) +
                ((Tw[4][t] + Tw[5][t]) + (Tw[6][t] + Tw[7][t]));
      pE[(size_t)bi * NROWS + j0 + t] = s;
    }
  }
}

// fold nslots slot-partials + unary -> lg; coef_out = 1-2*sigmoid(lg)
__global__ __launch_bounds__(128) void ppmv_reduce(const float* __restrict__ pE,
                                                   int nslots,
                                                   const float* __restrict__ unary,
                                                   float* __restrict__ coef_out,
                                                   float* __restrict__ lg_out) {
  int row = blockIdx.x * 128 + threadIdx.x;
  float acc = 0.f;
#pragma unroll 8
  for (int s = 0; s < nslots; ++s) acc += pE[(size_t)s * NROWS + row];
  float lg = unary[row] + acc;
  coef_out[row] = 1.f - 2.f / (1.f + __expf(-lg));
  if (lg_out) lg_out[row] = lg;
}

extern "C" void kernel_launch(void* const* d_in, const int* in_sizes, int n_in,
                              void* d_out, int out_size, void* d_ws, size_t ws_size,
                              hipStream_t stream) {
  const float* x   = (const float*)d_in[0];
  const float* W   = (const float*)d_in[1];
  const float* W1  = (const float*)d_in[2];
  const float* g1  = (const float*)d_in[4];
  const float* be1 = (const float*)d_in[5];
  const float* W2  = (const float*)d_in[6];
  const float* g2  = (const float*)d_in[8];
  const float* be2 = (const float*)d_in[9];
  const float* fcw = (const float*)d_in[10];
  const float* fcb = (const float*)d_in[11];
  float* out = (float*)d_out;

  char* ws = (char*)d_ws;
  unsigned short* hraw = (unsigned short*)(ws + 0);          // 8 MB (dead after bn_apply)
  float* pE128 = (float*)(ws + 0);                           // 4 MB (aliases hraw)
  float* pE64  = (float*)(ws + 4194304);                     // 2 MB (aliases hraw)
  unsigned short* fraw = (unsigned short*)(ws + 8388608);    // 4 MB
  float* pS1   = (float*)(ws + 12582912);                    // 256 KB
  float* pQ1   = (float*)(ws + 12845056);                    // 256 KB
  float* pS2   = (float*)(ws + 13107200);                    // 128 KB
  float* pQ2   = (float*)(ws + 13238272);                    // 128 KB
  float2* ab1  = (float2*)(ws + 13369344);                   // 4 KB
  float2* ab2  = (float2*)(ws + 13373440);                   // 2 KB
  unsigned short* fnorm = (unsigned short*)(ws + 13375488);  // 4 MB
  float* unary = (float*)(ws + 17569792);
  float* coefA = (float*)(ws + 17602560);
  float* coefB = (float*)(ws + 17635328);
  unsigned short* hb  = (unsigned short*)(ws + 17668096);    // 8 MB
  unsigned short* xb  = (unsigned short*)(ws + 26056704);    // 2 MB
  unsigned short* w1b = (unsigned short*)(ws + 28153856);    // 128 KB
  unsigned short* w2b = (unsigned short*)(ws + 28284928);    // 256 KB
  unsigned short* PP  = (unsigned short*)(ws + 28547072);    // 128 MB
  if (ws_size < (size_t)162764800) return;

  // casts (one kernel)
  cast3<<<608, 256, 0, stream>>>(x, W1, W2, xb, w1b, w2b);
  // layer 1: hraw = x @ W1^T (bf16 out + fused col stats); BN; leaky -> hb
  gemm_bt_mfma_stats<<<dim3(128, 8), 256, 0, stream>>>(xb, w1b, hraw, pS1, pQ1, 512, 128);
  bn_finalize<<<2, 256, 0, stream>>>(pS1, pQ1, g1, be1, ab1, 512);
  bn_apply<<<2048, 256, 0, stream>>>(hraw, ab1, hb, 511);
  // layer 2: fraw = hb @ W2^T (bf16 out + fused col stats); BN+rowfn fused
  gemm_bt_mfma_stats<<<dim3(128, 4), 256, 0, stream>>>(hb, w2b, fraw, pS2, pQ2, 256, 512);
  bn_finalize<<<1, 256, 0, stream>>>(pS2, pQ2, g2, be2, ab2, 256);
  bn_rowfn<<<2048, 256, 0, stream>>>(fraw, ab2, fcw, fcb, fnorm, unary, coefA);
  // PP upper triangle + fused iteration-1 partials (hraw dead; pE* alias it)
  ppbuild_sym<<<8256, 256, 0, stream>>>(fnorm, W, PP, coefA, pE128);
  ppmv_reduce<<<64, 128, 0, stream>>>(pE128, 128, unary, coefB,
                                      NITER == 1 ? out : nullptr);
  // iterations 2..10 (two kernels each; no grid.sync — ~125 us/sync on
  // 8-XCD MI355X, measured round 8; no fused fold — 65x redundant, round 11)
  float* cur = coefB; float* nxt = coefA;
  for (int it = 2; it <= NITER; ++it) {
    ppmv_sym<<<2080, 256, 0, stream>>>(PP, cur, pE64);
    ppmv_reduce<<<64, 128, 0, stream>>>(pE64, 64, unary, nxt,
                                        it == NITER ? out : nullptr);
    float* tmp = cur; cur = nxt; nxt = tmp;
  }
}

// Round 14
// 289.155 us; speedup vs baseline: 1.3281x; 1.1669x over previous
//
#include <hip/hip_runtime.h>
#include <hip/hip_bf16.h>

#define NROWS 8192
#define NITER 10
#define ESCALE 1048576.0f          // 2^20 fixed-point scale for E partials
#define EINV   (1.0f / 1048576.0f)

typedef __attribute__((ext_vector_type(8))) short bf16x8;
typedef __attribute__((ext_vector_type(8))) unsigned short u16x8;
typedef __attribute__((ext_vector_type(16))) float f32x16;

__device__ __forceinline__ float bf2f(unsigned short u) {
  union { float f; unsigned int i; } c; c.i = ((unsigned int)u) << 16; return c.f;
}
__device__ __forceinline__ unsigned short f2bf(float f) {
  unsigned int x = __float_as_uint(f);
  unsigned int r = (x + 0x7FFFu + ((x >> 16) & 1u)) >> 16;
  return (unsigned short)r;
}

// tril inversion, 128-wide grid (64x64 tiles) for ppbuild
#define TRIS(b) ((b) * (257 - (b)) / 2)
__device__ __forceinline__ void tril_decode(int L, int& bi, int& bj) {
  int b = (int)((257.0f - sqrtf((float)(66049 - 8 * L))) * 0.5f);
  if (b > 127) b = 127;
  if (b < 0) b = 0;
  while (b < 127 && TRIS(b + 1) <= L) ++b;
  while (b > 0 && TRIS(b) > L) --b;
  bi = b;
  bj = b + (L - TRIS(b));
}

// tril inversion, 64-wide grid (128x128 tiles) for ppmv
#define TRIS64(b) ((b) * (129 - (b)) / 2)
__device__ __forceinline__ void tril64_decode(int L, int& bi, int& bj) {
  int b = (int)((129.0f - sqrtf((float)(16641 - 8 * L))) * 0.5f);
  if (b > 63) b = 63;
  if (b < 0) b = 0;
  while (b < 63 && TRIS64(b + 1) <= L) ++b;
  while (b > 0 && TRIS64(b) > L) --b;
  bi = b;
  bj = b + (L - TRIS64(b));
}

// casts x, W1, W2 to bf16 (8 elems/thread) and zeroes Z0 (it-1 accumulator)
__global__ __launch_bounds__(256) void cast3(const float* __restrict__ x,
                                             const float* __restrict__ W1,
                                             const float* __restrict__ W2,
                                             unsigned short* __restrict__ xb,
                                             unsigned short* __restrict__ w1b,
                                             unsigned short* __restrict__ w2b,
                                             unsigned long long* __restrict__ Z0) {
  int idx = blockIdx.x * 256 + threadIdx.x;
  if (idx < NROWS) Z0[idx] = 0ull;
  const float* src; unsigned short* dst; int l;
  if (idx < 131072) { src = x; dst = xb; l = idx; }
  else if (idx < 139264) { src = W1; dst = w1b; l = idx - 131072; }
  else if (idx < 155648) { src = W2; dst = w2b; l = idx - 139264; }
  else return;
  const float4* p = (const float4*)src + (size_t)l * 2;
  float4 a = p[0], b = p[1];
  u16x8 o;
  o[0] = f2bf(a.x); o[1] = f2bf(a.y); o[2] = f2bf(a.z); o[3] = f2bf(a.w);
  o[4] = f2bf(b.x); o[5] = f2bf(b.y); o[6] = f2bf(b.z); o[7] = f2bf(b.w);
  *(u16x8*)(dst + (size_t)l * 8) = o;
}

// C[M,NN] = A[M,K] @ B[NN,K]^T (bf16 in, bf16 out) + fused per-column
// partial BN stats (sum, sumsq) from the fp32 accumulators.
__global__ __launch_bounds__(256) void gemm_bt_mfma_stats(
    const unsigned short* __restrict__ A, const unsigned short* __restrict__ B,
    unsigned short* __restrict__ Cb, float* __restrict__ pS, float* __restrict__ pQ,
    int NN, int K) {
  __shared__ __align__(16) unsigned short Asw[4096];
  __shared__ __align__(16) unsigned short Bsw[4096];
  __shared__ float Sarr[4][64], Qarr[4][64];
  const int i0 = blockIdx.x * 64, j0 = blockIdx.y * 64;
  const int t = threadIdx.x;
  const int lane = t & 63;
  const int wv = t >> 6;
  const int wi = wv >> 1, wj = wv & 1;
  const int khalf = lane >> 5;

  f32x16 acc;
#pragma unroll
  for (int r = 0; r < 16; ++r) acc[r] = 0.f;

  const int lrow = t >> 2;
  const int lgp = (t & 3) * 2;
  const int arow = wi * 32 + (lane & 31);
  const int brow = wj * 32 + (lane & 31);
  const int nc = K >> 6;
#pragma unroll 1
  for (int c = 0; c < nc; ++c) {
    const unsigned short* sa = A + (size_t)(i0 + lrow) * K + c * 64 + lgp * 8;
    const unsigned short* sb = B + (size_t)(j0 + lrow) * K + c * 64 + lgp * 8;
    u16x8 va0 = *(const u16x8*)(sa);
    u16x8 va1 = *(const u16x8*)(sa + 8);
    u16x8 vb0 = *(const u16x8*)(sb);
    u16x8 vb1 = *(const u16x8*)(sb + 8);
    __syncthreads();
    int s0 = (lgp ^ (lrow & 7)) * 8;
    int s1 = ((lgp + 1) ^ (lrow & 7)) * 8;
    *(u16x8*)&Asw[lrow * 64 + s0] = va0;
    *(u16x8*)&Asw[lrow * 64 + s1] = va1;
    *(u16x8*)&Bsw[lrow * 64 + s0] = vb0;
    *(u16x8*)&Bsw[lrow * 64 + s1] = vb1;
    __syncthreads();
#pragma unroll
    for (int s = 0; s < 4; ++s) {
      int slot = s * 2 + khalf;
      bf16x8 a = *(const bf16x8*)&Asw[arow * 64 + ((slot ^ (arow & 7)) * 8)];
      bf16x8 b = *(const bf16x8*)&Bsw[brow * 64 + ((slot ^ (brow & 7)) * 8)];
      acc = __builtin_amdgcn_mfma_f32_32x32x16_bf16(a, b, acc, 0, 0, 0);
    }
  }
  // epilogue: bf16 store + per-lane column stats (16 rows of column coll)
  float s = 0.f, q = 0.f;
#pragma unroll
  for (int r = 0; r < 16; ++r) {
    int rowl = (r & 3) + 8 * (r >> 2) + 4 * khalf;
    int coll = lane & 31;
    float v = acc[r];
    s += v; q += v * v;
    Cb[(size_t)(i0 + wi * 32 + rowl) * NN + j0 + wj * 32 + coll] = f2bf(v);
  }
  Sarr[wv][lane] = s;
  Qarr[wv][lane] = q;
  __syncthreads();
  if (t < 64) {  // column c of block: fold 4 deterministic contributions
    int wjc = t >> 5, coll = t & 31;
    float st = (Sarr[wjc][coll] + Sarr[wjc][coll + 32]) +
               (Sarr[wjc + 2][coll] + Sarr[wjc + 2][coll + 32]);
    float qt = (Qarr[wjc][coll] + Qarr[wjc][coll + 32]) +
               (Qarr[wjc + 2][coll] + Qarr[wjc + 2][coll + 32]);
    pS[(size_t)blockIdx.x * NN + j0 + t] = st;
    pQ[(size_t)blockIdx.x * NN + j0 + t] = qt;
  }
}

// fold 128 row-block partial stats -> per-column scale/shift
__global__ void bn_finalize(const float* __restrict__ pS, const float* __restrict__ pQ,
                            const float* __restrict__ g, const float* __restrict__ be,
                            float2* __restrict__ ab, int C) {
  int c = blockIdx.x * 256 + threadIdx.x;
  if (c >= C) return;
  float s = 0.f, q = 0.f;
  for (int r = 0; r < 128; ++r) { s += pS[(size_t)r * C + c]; q += pQ[(size_t)r * C + c]; }
  const float invM = 1.f / 8192.f;
  float mu = s * invM;
  float var = q * invM - mu * mu;
  float rstd = rsqrtf(var + 1e-5f);
  float a = g[c] * rstd;
  ab[c] = make_float2(a, be[c] - mu * a);
}

// hb = leaky_relu(a*hraw + b), bf16 -> bf16, 8 elems/thread
__global__ __launch_bounds__(256) void bn_apply(const unsigned short* __restrict__ hraw,
                                                const float2* __restrict__ ab,
                                                unsigned short* __restrict__ hb,
                                                int Cmask) {
  size_t idx = (size_t)blockIdx.x * 256 + threadIdx.x;
  u16x8 v = *(const u16x8*)(hraw + idx * 8);
  int cb = (int)((idx * 8) & (size_t)Cmask);
  u16x8 o;
#pragma unroll
  for (int k = 0; k < 8; ++k) {
    float2 a = ab[cb + k];
    float r = a.x * bf2f(v[k]) + a.y;
    r = r >= 0.f ? r : 0.01f * r;
    o[k] = f2bf(r);
  }
  *(u16x8*)(hb + idx * 8) = o;
}

// fused: feats-BN + leaky + row norm + fc logit; writes fnorm bf16, unary, coef0
__global__ __launch_bounds__(256) void bn_rowfn(const unsigned short* __restrict__ fraw,
                                                const float2* __restrict__ ab,
                                                const float* __restrict__ fcw,
                                                const float* __restrict__ fcb,
                                                unsigned short* __restrict__ fnorm,
                                                float* __restrict__ unary,
                                                float* __restrict__ coef0) {
  const int lane = threadIdx.x & 63;
  const int row = blockIdx.x * 4 + (threadIdx.x >> 6);
  ushort4 v4 = *(const ushort4*)(fraw + (size_t)row * 256 + lane * 4);
  float4 w = *(const float4*)(fcw + lane * 4);
  int c = lane * 4;
  float2 a0 = ab[c], a1 = ab[c + 1], a2 = ab[c + 2], a3 = ab[c + 3];
  float f0 = a0.x * bf2f(v4.x) + a0.y; f0 = f0 >= 0.f ? f0 : 0.01f * f0;
  float f1 = a1.x * bf2f(v4.y) + a1.y; f1 = f1 >= 0.f ? f1 : 0.01f * f1;
  float f2 = a2.x * bf2f(v4.z) + a2.y; f2 = f2 >= 0.f ? f2 : 0.01f * f2;
  float f3 = a3.x * bf2f(v4.w) + a3.y; f3 = f3 >= 0.f ? f3 : 0.01f * f3;
  float ssq = f0 * f0 + f1 * f1 + f2 * f2 + f3 * f3;
  float dot = f0 * w.x + f1 * w.y + f2 * w.z + f3 * w.w;
#pragma unroll
  for (int o = 32; o; o >>= 1) { ssq += __shfl_xor(ssq, o); dot += __shfl_xor(dot, o); }
  float rfn = rsqrtf(ssq);
  *(ushort4*)(fnorm + (size_t)row * 256 + lane * 4) =
      make_ushort4(f2bf(f0 * rfn), f2bf(f1 * rfn), f2bf(f2 * rfn), f2bf(f3 * rfn));
  if (lane == 0) {
    float lg = dot + fcb[0];
    unary[row] = lg;
    coef0[row] = 1.f - 2.f / (1.f + __expf(-lg));
  }
}

// PP[i,j] = (fnorm_i . fnorm_j) * 0.5*(W[i,j]+W[j,i]); upper-triangle only.
__global__ __launch_bounds__(256) void ppbuild_sym(const unsigned short* __restrict__ fnorm,
                                                   const float* __restrict__ W,
                                                   unsigned short* __restrict__ PP) {
  int bi, bj;
  tril_decode(blockIdx.x, bi, bj);
  const int i0 = bi * 64, j0 = bj * 64;

  __shared__ __align__(16) unsigned char shm[18944];
  unsigned short* Asw = (unsigned short*)shm;
  unsigned short* Bsw = (unsigned short*)shm + 4736;
  float (*Wt)[68] = (float(*)[68])shm;
  unsigned short* OutD = (unsigned short*)shm;

  const int t = threadIdx.x;
  const int lane = t & 63;
  const int wv = t >> 6;
  const int wi = wv >> 1, wj = wv & 1;
  const int khalf = lane >> 5;

  f32x16 acc;
#pragma unroll
  for (int r = 0; r < 16; ++r) acc[r] = 0.f;

  const int lrow = t >> 2;
  const int lgp = (t & 3) * 2;
  const int arow = wi * 32 + (lane & 31);
  const int brow = wj * 32 + (lane & 31);
#pragma unroll 1
  for (int c = 0; c < 4; ++c) {
    const unsigned short* sa = fnorm + (size_t)(i0 + lrow) * 256 + c * 64 + lgp * 8;
    const unsigned short* sb = fnorm + (size_t)(j0 + lrow) * 256 + c * 64 + lgp * 8;
    u16x8 va0 = *(const u16x8*)(sa);
    u16x8 va1 = *(const u16x8*)(sa + 8);
    u16x8 vb0 = *(const u16x8*)(sb);
    u16x8 vb1 = *(const u16x8*)(sb + 8);
    __syncthreads();
    int s0 = (lgp ^ (lrow & 7)) * 8;
    int s1 = ((lgp + 1) ^ (lrow & 7)) * 8;
    *(u16x8*)&Asw[lrow * 64 + s0] = va0;
    *(u16x8*)&Asw[lrow * 64 + s1] = va1;
    *(u16x8*)&Bsw[lrow * 64 + s0] = vb0;
    *(u16x8*)&Bsw[lrow * 64 + s1] = vb1;
    __syncthreads();
#pragma unroll
    for (int s = 0; s < 4; ++s) {
      int slot = s * 2 + khalf;
      bf16x8 a = *(const bf16x8*)&Asw[arow * 64 + ((slot ^ (arow & 7)) * 8)];
      bf16x8 b = *(const bf16x8*)&Bsw[brow * 64 + ((slot ^ (brow & 7)) * 8)];
      acc = __builtin_amdgcn_mfma_f32_32x32x16_bf16(a, b, acc, 0, 0, 0);
    }
  }

  __syncthreads();
  {
    const int j = t >> 2, cb = (t & 3) * 16;
    const float* src = W + (size_t)(j0 + j) * NROWS + i0 + cb;
#pragma unroll
    for (int q = 0; q < 4; ++q) {
      float4 v = *(const float4*)(src + q * 4);
      Wt[j][cb + q * 4 + 0] = v.x; Wt[j][cb + q * 4 + 1] = v.y;
      Wt[j][cb + q * 4 + 2] = v.z; Wt[j][cb + q * 4 + 3] = v.w;
    }
  }
  __syncthreads();
  unsigned short pb[16];
#pragma unroll
  for (int r = 0; r < 16; ++r) {
    int rowl = (r & 3) + 8 * (r >> 2) + 4 * khalf;
    int coll = lane & 31;
    int il = wi * 32 + rowl, jl = wj * 32 + coll;
    float wd = W[(size_t)(i0 + il) * NROWS + (j0 + jl)];
    float ws = 0.5f * (wd + Wt[jl][il]);
    pb[r] = f2bf(acc[r] * ws);
  }
  __syncthreads();
#pragma unroll
  for (int r = 0; r < 16; ++r) {
    int rowl = (r & 3) + 8 * (r >> 2) + 4 * khalf;
    int coll = lane & 31;
    OutD[(wi * 32 + rowl) * 74 + wj * 32 + coll] = pb[r];
  }
  __syncthreads();
  const int row = t >> 3;
  const int seg = t & 7;
#pragma unroll
  for (int q = 0; q < 2; ++q) {
    int rr = row + q * 32;
    const unsigned int* pd = (const unsigned int*)(OutD + rr * 74 + seg * 8);
    union { u16x8 v; unsigned int u[4]; } dd;
#pragma unroll
    for (int k = 0; k < 4; ++k) dd.u[k] = pd[k];
    *(u16x8*)(PP + (size_t)(i0 + rr) * NROWS + j0 + seg * 8) = dd.v;
  }
}

// One full iteration per launch: per block, read coef inputs (Zprev int64 is
// FULLY accumulated at the kernel boundary — one 8B read per row, no fold
// redundancy), compute 128x128 symmetric tile partials, accumulate into Zacc
// via int64 fixed-point atomics (integer add = order-independent =>
// deterministic). Diagonal blocks zero Zzero for use two iterations later.
__global__ __launch_bounds__(256) void ppmv_atomic(
    const unsigned short* __restrict__ PP,
    const float* __restrict__ unary,
    const long long* __restrict__ Zprev,     // null on iteration 1
    const float* __restrict__ coef0,
    unsigned long long* __restrict__ Zacc,
    unsigned long long* __restrict__ Zzero) { // null on last iteration
  int bi, bj;
  tril64_decode(blockIdx.x, bi, bj);
  const int i0 = bi * 128, j0 = bj * 128;
  const int t = threadIdx.x;

  __shared__ __align__(16) unsigned short tile[128][132];  // 33792 B
  __shared__ float cj[128], ci[128];
  __shared__ float Tw[8][128];

  // issue PP tile loads into registers first (L3/HBM latency overlaps rest)
  const int r = t >> 1, h = (t & 1) * 64;
  u16x8 tv[8];
  {
    const unsigned short* src = PP + (size_t)(i0 + r) * NROWS + j0 + h;
#pragma unroll
    for (int q = 0; q < 8; ++q) tv[q] = *(const u16x8*)(src + q * 8);
  }
  // zero duty: diagonal band zeroes its 128 rows of the buffer that will be
  // accumulated two iterations from now (untouched by anyone this iteration)
  if (bi == bj && Zzero != nullptr && t < 128) Zzero[i0 + t] = 0ull;
  // coef for this thread's assigned row
  {
    int myrow = (t < 128) ? (j0 + t) : (i0 + (t - 128));
    float c;
    if (Zprev) {
      float lg = unary[myrow] + (float)Zprev[myrow] * EINV;
      c = 1.f - 2.f / (1.f + __expf(-lg));
    } else {
      c = coef0[myrow];
    }
    if (t < 128) cj[t] = c;
    else ci[t - 128] = c;
  }
#pragma unroll
  for (int q = 0; q < 8; ++q) *(u16x8*)&tile[r][h + q * 8] = tv[q];
  __syncthreads();
  // row sums (D): thread owns half a row; lane pair reduces; direct atomic
  {
    float a = 0.f;
#pragma unroll
    for (int q = 0; q < 8; ++q) {
      u16x8 v = *(const u16x8*)&tile[r][h + q * 8];
      float4 c0 = *(const float4*)&cj[h + q * 8];
      float4 c1 = *(const float4*)&cj[h + q * 8 + 4];
      a += bf2f(v[0]) * c0.x + bf2f(v[1]) * c0.y + bf2f(v[2]) * c0.z + bf2f(v[3]) * c0.w;
      a += bf2f(v[4]) * c1.x + bf2f(v[5]) * c1.y + bf2f(v[6]) * c1.z + bf2f(v[7]) * c1.w;
    }
    a += __shfl_xor(a, 1);
    if ((t & 1) == 0)
      atomicAdd(&Zacc[i0 + r], (unsigned long long)(long long)llrintf(a * ESCALE));
  }
  // col sums (T): thread owns 4 cols x 16 rows; fold 8 groups in LDS
  {
    const int c4 = (t & 31) * 4, rg = t >> 5;
    float a0 = 0.f, a1 = 0.f, a2 = 0.f, a3 = 0.f;
#pragma unroll
    for (int k = 0; k < 16; ++k) {
      int row = rg * 16 + k;
      ushort4 v = *(const ushort4*)&tile[row][c4];
      float s = ci[row];
      a0 += bf2f(v.x) * s; a1 += bf2f(v.y) * s;
      a2 += bf2f(v.z) * s; a3 += bf2f(v.w) * s;
    }
    Tw[rg][c4] = a0; Tw[rg][c4 + 1] = a1;
    Tw[rg][c4 + 2] = a2; Tw[rg][c4 + 3] = a3;
  }
  __syncthreads();
  if (t < 128 && bi != bj) {
    float s = ((Tw[0][t] + Tw[1][t]) + (Tw[2][t] + Tw[3][t])) +
              ((Tw[4][t] + Tw[5][t]) + (Tw[6][t] + Tw[7][t]));
    atomicAdd(&Zacc[j0 + t], (unsigned long long)(long long)llrintf(s * ESCALE));
  }
}

// final: lg = unary + Zfinal*EINV -> out
__global__ __launch_bounds__(256) void final_out(const long long* __restrict__ Z,
                                                 const float* __restrict__ unary,
                                                 float* __restrict__ out) {
  int row = blockIdx.x * 256 + threadIdx.x;
  out[row] = unary[row] + (float)Z[row] * EINV;
}

extern "C" void kernel_launch(void* const* d_in, const int* in_sizes, int n_in,
                              void* d_out, int out_size, void* d_ws, size_t ws_size,
                              hipStream_t stream) {
  const float* x   = (const float*)d_in[0];
  const float* W   = (const float*)d_in[1];
  const float* W1  = (const float*)d_in[2];
  const float* g1  = (const float*)d_in[4];
  const float* be1 = (const float*)d_in[5];
  const float* W2  = (const float*)d_in[6];
  const float* g2  = (const float*)d_in[8];
  const float* be2 = (const float*)d_in[9];
  const float* fcw = (const float*)d_in[10];
  const float* fcb = (const float*)d_in[11];
  float* out = (float*)d_out;

  char* ws = (char*)d_ws;
  unsigned short* hraw = (unsigned short*)(ws + 0);          // 8 MB (dead after bn_apply)
  unsigned short* fraw = (unsigned short*)(ws + 8388608);    // 4 MB
  float* pS1   = (float*)(ws + 12582912);                    // 256 KB
  float* pQ1   = (float*)(ws + 12845056);                    // 256 KB
  float* pS2   = (float*)(ws + 13107200);                    // 128 KB
  float* pQ2   = (float*)(ws + 13238272);                    // 128 KB
  float2* ab1  = (float2*)(ws + 13369344);                   // 4 KB
  float2* ab2  = (float2*)(ws + 13373440);                   // 2 KB
  unsigned short* fnorm = (unsigned short*)(ws + 13375488);  // 4 MB
  float* unary = (float*)(ws + 17569792);
  float* coefA = (float*)(ws + 17602560);
  unsigned short* hb  = (unsigned short*)(ws + 17668096);    // 8 MB
  unsigned short* xb  = (unsigned short*)(ws + 26056704);    // 2 MB
  unsigned short* w1b = (unsigned short*)(ws + 28153856);    // 128 KB
  unsigned short* w2b = (unsigned short*)(ws + 28284928);    // 256 KB
  unsigned short* PP  = (unsigned short*)(ws + 28547072);    // 128 MB -> 162764800
  unsigned long long* Z0 = (unsigned long long*)(ws + 162764800);  // 64 KB
  unsigned long long* Z1 = (unsigned long long*)(ws + 162830336);  // 64 KB
  unsigned long long* Z2 = (unsigned long long*)(ws + 162895872);  // 64 KB
  if (ws_size < (size_t)162961408) return;
  unsigned long long* Z[3] = {Z0, Z1, Z2};

  // casts (one kernel; also zeroes Z0 for iteration 1)
  cast3<<<608, 256, 0, stream>>>(x, W1, W2, xb, w1b, w2b, Z0);
  // layer 1: hraw = x @ W1^T (bf16 out + fused col stats); BN; leaky -> hb
  gemm_bt_mfma_stats<<<dim3(128, 8), 256, 0, stream>>>(xb, w1b, hraw, pS1, pQ1, 512, 128);
  bn_finalize<<<2, 256, 0, stream>>>(pS1, pQ1, g1, be1, ab1, 512);
  bn_apply<<<2048, 256, 0, stream>>>(hraw, ab1, hb, 511);
  // layer 2: fraw = hb @ W2^T (bf16 out + fused col stats); BN+rowfn fused
  gemm_bt_mfma_stats<<<dim3(128, 4), 256, 0, stream>>>(hb, w2b, fraw, pS2, pQ2, 256, 512);
  bn_finalize<<<1, 256, 0, stream>>>(pS2, pQ2, g2, be2, ab2, 256);
  bn_rowfn<<<2048, 256, 0, stream>>>(fraw, ab2, fcw, fcb, fnorm, unary, coefA);
  // PP upper triangle
  ppbuild_sym<<<8256, 256, 0, stream>>>(fnorm, W, PP);
  // 10 iterations, ONE kernel each (int64 fixed-point atomics: deterministic;
  // no per-iter reduce kernel, no grid.sync (~125 us/sync, round 8), no
  // redundant fp32 fold (65x fan-in, round 11))
  for (int it = 1; it <= NITER; ++it) {
    const long long* zp = (it == 1) ? nullptr : (const long long*)Z[(it + 1) % 3];
    unsigned long long* za = Z[(it - 1) % 3];
    unsigned long long* zz = (it < NITER) ? Z[it % 3] : nullptr;
    ppmv_atomic<<<2080, 256, 0, stream>>>(PP, unary, zp, coefA, za, zz);
  }
  final_out<<<32, 256, 0, stream>>>((const long long*)Z[(NITER - 1) % 3], unary, out);
}

// Round 15
// 286.011 us; speedup vs baseline: 1.3427x; 1.0110x over previous
//
#include <hip/hip_runtime.h>
#include <hip/hip_bf16.h>

#define NROWS 8192
#define NITER 10
#define ESCALE 1048576.0f          // 2^20 fixed-point scale for E partials
#define EINV   (1.0f / 1048576.0f)

typedef __attribute__((ext_vector_type(8))) short bf16x8;
typedef __attribute__((ext_vector_type(8))) unsigned short u16x8;
typedef __attribute__((ext_vector_type(16))) float f32x16;

__device__ __forceinline__ float bf2f(unsigned short u) {
  union { float f; unsigned int i; } c; c.i = ((unsigned int)u) << 16; return c.f;
}
__device__ __forceinline__ unsigned short f2bf(float f) {
  unsigned int x = __float_as_uint(f);
  unsigned int r = (x + 0x7FFFu + ((x >> 16) & 1u)) >> 16;
  return (unsigned short)r;
}

// tril inversion, 128-wide grid (64x64 tiles) for ppbuild
#define TRIS(b) ((b) * (257 - (b)) / 2)
__device__ __forceinline__ void tril_decode(int L, int& bi, int& bj) {
  int b = (int)((257.0f - sqrtf((float)(66049 - 8 * L))) * 0.5f);
  if (b > 127) b = 127;
  if (b < 0) b = 0;
  while (b < 127 && TRIS(b + 1) <= L) ++b;
  while (b > 0 && TRIS(b) > L) --b;
  bi = b;
  bj = b + (L - TRIS(b));
}

// tril inversion, 64-wide grid (128x128 tiles) for ppmv
#define TRIS64(b) ((b) * (129 - (b)) / 2)
__device__ __forceinline__ void tril64_decode(int L, int& bi, int& bj) {
  int b = (int)((129.0f - sqrtf((float)(16641 - 8 * L))) * 0.5f);
  if (b > 63) b = 63;
  if (b < 0) b = 0;
  while (b < 63 && TRIS64(b + 1) <= L) ++b;
  while (b > 0 && TRIS64(b) > L) --b;
  bi = b;
  bj = b + (L - TRIS64(b));
}

// casts x, W1, W2 to bf16 (8 elems/thread) and zeroes Z0 (it-1 accumulator)
__global__ __launch_bounds__(256) void cast3(const float* __restrict__ x,
                                             const float* __restrict__ W1,
                                             const float* __restrict__ W2,
                                             unsigned short* __restrict__ xb,
                                             unsigned short* __restrict__ w1b,
                                             unsigned short* __restrict__ w2b,
                                             unsigned long long* __restrict__ Z0) {
  int idx = blockIdx.x * 256 + threadIdx.x;
  if (idx < NROWS) Z0[idx] = 0ull;
  const float* src; unsigned short* dst; int l;
  if (idx < 131072) { src = x; dst = xb; l = idx; }
  else if (idx < 139264) { src = W1; dst = w1b; l = idx - 131072; }
  else if (idx < 155648) { src = W2; dst = w2b; l = idx - 139264; }
  else return;
  const float4* p = (const float4*)src + (size_t)l * 2;
  float4 a = p[0], b = p[1];
  u16x8 o;
  o[0] = f2bf(a.x); o[1] = f2bf(a.y); o[2] = f2bf(a.z); o[3] = f2bf(a.w);
  o[4] = f2bf(b.x); o[5] = f2bf(b.y); o[6] = f2bf(b.z); o[7] = f2bf(b.w);
  *(u16x8*)(dst + (size_t)l * 8) = o;
}

// C[M,NN] = A[M,K] @ B[NN,K]^T (bf16 in, bf16 out) + fused per-column
// partial BN stats (sum, sumsq) from the fp32 accumulators.
__global__ __launch_bounds__(256) void gemm_bt_mfma_stats(
    const unsigned short* __restrict__ A, const unsigned short* __restrict__ B,
    unsigned short* __restrict__ Cb, float* __restrict__ pS, float* __restrict__ pQ,
    int NN, int K) {
  __shared__ __align__(16) unsigned short Asw[4096];
  __shared__ __align__(16) unsigned short Bsw[4096];
  __shared__ float Sarr[4][64], Qarr[4][64];
  const int i0 = blockIdx.x * 64, j0 = blockIdx.y * 64;
  const int t = threadIdx.x;
  const int lane = t & 63;
  const int wv = t >> 6;
  const int wi = wv >> 1, wj = wv & 1;
  const int khalf = lane >> 5;

  f32x16 acc;
#pragma unroll
  for (int r = 0; r < 16; ++r) acc[r] = 0.f;

  const int lrow = t >> 2;
  const int lgp = (t & 3) * 2;
  const int arow = wi * 32 + (lane & 31);
  const int brow = wj * 32 + (lane & 31);
  const int nc = K >> 6;
#pragma unroll 1
  for (int c = 0; c < nc; ++c) {
    const unsigned short* sa = A + (size_t)(i0 + lrow) * K + c * 64 + lgp * 8;
    const unsigned short* sb = B + (size_t)(j0 + lrow) * K + c * 64 + lgp * 8;
    u16x8 va0 = *(const u16x8*)(sa);
    u16x8 va1 = *(const u16x8*)(sa + 8);
    u16x8 vb0 = *(const u16x8*)(sb);
    u16x8 vb1 = *(const u16x8*)(sb + 8);
    __syncthreads();
    int s0 = (lgp ^ (lrow & 7)) * 8;
    int s1 = ((lgp + 1) ^ (lrow & 7)) * 8;
    *(u16x8*)&Asw[lrow * 64 + s0] = va0;
    *(u16x8*)&Asw[lrow * 64 + s1] = va1;
    *(u16x8*)&Bsw[lrow * 64 + s0] = vb0;
    *(u16x8*)&Bsw[lrow * 64 + s1] = vb1;
    __syncthreads();
#pragma unroll
    for (int s = 0; s < 4; ++s) {
      int slot = s * 2 + khalf;
      bf16x8 a = *(const bf16x8*)&Asw[arow * 64 + ((slot ^ (arow & 7)) * 8)];
      bf16x8 b = *(const bf16x8*)&Bsw[brow * 64 + ((slot ^ (brow & 7)) * 8)];
      acc = __builtin_amdgcn_mfma_f32_32x32x16_bf16(a, b, acc, 0, 0, 0);
    }
  }
  // epilogue: bf16 store + per-lane column stats (16 rows of column coll)
  float s = 0.f, q = 0.f;
#pragma unroll
  for (int r = 0; r < 16; ++r) {
    int rowl = (r & 3) + 8 * (r >> 2) + 4 * khalf;
    int coll = lane & 31;
    float v = acc[r];
    s += v; q += v * v;
    Cb[(size_t)(i0 + wi * 32 + rowl) * NN + j0 + wj * 32 + coll] = f2bf(v);
  }
  Sarr[wv][lane] = s;
  Qarr[wv][lane] = q;
  __syncthreads();
  if (t < 64) {  // column c of block: fold 4 deterministic contributions
    int wjc = t >> 5, coll = t & 31;
    float st = (Sarr[wjc][coll] + Sarr[wjc][coll + 32]) +
               (Sarr[wjc + 2][coll] + Sarr[wjc + 2][coll + 32]);
    float qt = (Qarr[wjc][coll] + Qarr[wjc][coll + 32]) +
               (Qarr[wjc + 2][coll] + Qarr[wjc + 2][coll + 32]);
    pS[(size_t)blockIdx.x * NN + j0 + t] = st;
    pQ[(size_t)blockIdx.x * NN + j0 + t] = qt;
  }
}

// fold 128 row-block partial stats -> per-column scale/shift
__global__ void bn_finalize(const float* __restrict__ pS, const float* __restrict__ pQ,
                            const float* __restrict__ g, const float* __restrict__ be,
                            float2* __restrict__ ab, int C) {
  int c = blockIdx.x * 256 + threadIdx.x;
  if (c >= C) return;
  float s = 0.f, q = 0.f;
  for (int r = 0; r < 128; ++r) { s += pS[(size_t)r * C + c]; q += pQ[(size_t)r * C + c]; }
  const float invM = 1.f / 8192.f;
  float mu = s * invM;
  float var = q * invM - mu * mu;
  float rstd = rsqrtf(var + 1e-5f);
  float a = g[c] * rstd;
  ab[c] = make_float2(a, be[c] - mu * a);
}

// hb = leaky_relu(a*hraw + b), bf16 -> bf16, 8 elems/thread
__global__ __launch_bounds__(256) void bn_apply(const unsigned short* __restrict__ hraw,
                                                const float2* __restrict__ ab,
                                                unsigned short* __restrict__ hb,
                                                int Cmask) {
  size_t idx = (size_t)blockIdx.x * 256 + threadIdx.x;
  u16x8 v = *(const u16x8*)(hraw + idx * 8);
  int cb = (int)((idx * 8) & (size_t)Cmask);
  u16x8 o;
#pragma unroll
  for (int k = 0; k < 8; ++k) {
    float2 a = ab[cb + k];
    float r = a.x * bf2f(v[k]) + a.y;
    r = r >= 0.f ? r : 0.01f * r;
    o[k] = f2bf(r);
  }
  *(u16x8*)(hb + idx * 8) = o;
}

// fused: feats-BN + leaky + row norm + fc logit; writes fnorm bf16, unary, coef0
__global__ __launch_bounds__(256) void bn_rowfn(const unsigned short* __restrict__ fraw,
                                                const float2* __restrict__ ab,
                                                const float* __restrict__ fcw,
                                                const float* __restrict__ fcb,
                                                unsigned short* __restrict__ fnorm,
                                                float* __restrict__ unary,
                                                float* __restrict__ coef0) {
  const int lane = threadIdx.x & 63;
  const int row = blockIdx.x * 4 + (threadIdx.x >> 6);
  ushort4 v4 = *(const ushort4*)(fraw + (size_t)row * 256 + lane * 4);
  float4 w = *(const float4*)(fcw + lane * 4);
  int c = lane * 4;
  float2 a0 = ab[c], a1 = ab[c + 1], a2 = ab[c + 2], a3 = ab[c + 3];
  float f0 = a0.x * bf2f(v4.x) + a0.y; f0 = f0 >= 0.f ? f0 : 0.01f * f0;
  float f1 = a1.x * bf2f(v4.y) + a1.y; f1 = f1 >= 0.f ? f1 : 0.01f * f1;
  float f2 = a2.x * bf2f(v4.z) + a2.y; f2 = f2 >= 0.f ? f2 : 0.01f * f2;
  float f3 = a3.x * bf2f(v4.w) + a3.y; f3 = f3 >= 0.f ? f3 : 0.01f * f3;
  float ssq = f0 * f0 + f1 * f1 + f2 * f2 + f3 * f3;
  float dot = f0 * w.x + f1 * w.y + f2 * w.z + f3 * w.w;
#pragma unroll
  for (int o = 32; o; o >>= 1) { ssq += __shfl_xor(ssq, o); dot += __shfl_xor(dot, o); }
  float rfn = rsqrtf(ssq);
  *(ushort4*)(fnorm + (size_t)row * 256 + lane * 4) =
      make_ushort4(f2bf(f0 * rfn), f2bf(f1 * rfn), f2bf(f2 * rfn), f2bf(f3 * rfn));
  if (lane == 0) {
    float lg = dot + fcb[0];
    unary[row] = lg;
    coef0[row] = 1.f - 2.f / (1.f + __expf(-lg));
  }
}

// PP[i,j] = (fnorm_i . fnorm_j) * 0.5*(W[i,j]+W[j,i]); upper-triangle only.
// W tiles (transposed + direct) are PREFETCHED into registers before the
// MFMA K-loop so their HBM latency hides under it (async-STAGE split).
__global__ __launch_bounds__(256) void ppbuild_sym(const unsigned short* __restrict__ fnorm,
                                                   const float* __restrict__ W,
                                                   unsigned short* __restrict__ PP) {
  int bi, bj;
  tril_decode(blockIdx.x, bi, bj);
  const int i0 = bi * 64, j0 = bj * 64;

  __shared__ __align__(16) unsigned char shm[18944];
  unsigned short* Asw = (unsigned short*)shm;
  unsigned short* Bsw = (unsigned short*)shm + 4736;
  float (*Wt)[68] = (float(*)[68])shm;
  unsigned short* OutD = (unsigned short*)shm;

  const int t = threadIdx.x;
  const int lane = t & 63;
  const int wv = t >> 6;
  const int wi = wv >> 1, wj = wv & 1;
  const int khalf = lane >> 5;

  // ---- prefetch W into registers (latency hides under K-loop) ----
  const int jW = t >> 2, cbW = (t & 3) * 16;
  const float* srcT = W + (size_t)(j0 + jW) * NROWS + i0 + cbW;
  float4 wtv[4];
#pragma unroll
  for (int q = 0; q < 4; ++q) wtv[q] = *(const float4*)(srcT + q * 4);
  float wdv[16];
#pragma unroll
  for (int r = 0; r < 16; ++r) {
    int rowl = (r & 3) + 8 * (r >> 2) + 4 * khalf;
    wdv[r] = W[(size_t)(i0 + wi * 32 + rowl) * NROWS + (j0 + wj * 32 + (lane & 31))];
  }
  __builtin_amdgcn_sched_barrier(0);  // keep the 20 loads issued up-front

  f32x16 acc;
#pragma unroll
  for (int r = 0; r < 16; ++r) acc[r] = 0.f;

  const int lrow = t >> 2;
  const int lgp = (t & 3) * 2;
  const int arow = wi * 32 + (lane & 31);
  const int brow = wj * 32 + (lane & 31);
#pragma unroll 1
  for (int c = 0; c < 4; ++c) {
    const unsigned short* sa = fnorm + (size_t)(i0 + lrow) * 256 + c * 64 + lgp * 8;
    const unsigned short* sb = fnorm + (size_t)(j0 + lrow) * 256 + c * 64 + lgp * 8;
    u16x8 va0 = *(const u16x8*)(sa);
    u16x8 va1 = *(const u16x8*)(sa + 8);
    u16x8 vb0 = *(const u16x8*)(sb);
    u16x8 vb1 = *(const u16x8*)(sb + 8);
    __syncthreads();
    int s0 = (lgp ^ (lrow & 7)) * 8;
    int s1 = ((lgp + 1) ^ (lrow & 7)) * 8;
    *(u16x8*)&Asw[lrow * 64 + s0] = va0;
    *(u16x8*)&Asw[lrow * 64 + s1] = va1;
    *(u16x8*)&Bsw[lrow * 64 + s0] = vb0;
    *(u16x8*)&Bsw[lrow * 64 + s1] = vb1;
    __syncthreads();
#pragma unroll
    for (int s = 0; s < 4; ++s) {
      int slot = s * 2 + khalf;
      bf16x8 a = *(const bf16x8*)&Asw[arow * 64 + ((slot ^ (arow & 7)) * 8)];
      bf16x8 b = *(const bf16x8*)&Bsw[brow * 64 + ((slot ^ (brow & 7)) * 8)];
      acc = __builtin_amdgcn_mfma_f32_32x32x16_bf16(a, b, acc, 0, 0, 0);
    }
  }

  __syncthreads();   // done reading Asw/Bsw; LDS becomes Wt
  {
#pragma unroll
    for (int q = 0; q < 4; ++q) {
      Wt[jW][cbW + q * 4 + 0] = wtv[q].x; Wt[jW][cbW + q * 4 + 1] = wtv[q].y;
      Wt[jW][cbW + q * 4 + 2] = wtv[q].z; Wt[jW][cbW + q * 4 + 3] = wtv[q].w;
    }
  }
  __syncthreads();
  unsigned short pb[16];
#pragma unroll
  for (int r = 0; r < 16; ++r) {
    int rowl = (r & 3) + 8 * (r >> 2) + 4 * khalf;
    int coll = lane & 31;
    int il = wi * 32 + rowl, jl = wj * 32 + coll;
    float ws = 0.5f * (wdv[r] + Wt[jl][il]);
    pb[r] = f2bf(acc[r] * ws);
  }
  __syncthreads();
#pragma unroll
  for (int r = 0; r < 16; ++r) {
    int rowl = (r & 3) + 8 * (r >> 2) + 4 * khalf;
    int coll = lane & 31;
    OutD[(wi * 32 + rowl) * 74 + wj * 32 + coll] = pb[r];
  }
  __syncthreads();
  const int row = t >> 3;
  const int seg = t & 7;
#pragma unroll
  for (int q = 0; q < 2; ++q) {
    int rr = row + q * 32;
    const unsigned int* pd = (const unsigned int*)(OutD + rr * 74 + seg * 8);
    union { u16x8 v; unsigned int u[4]; } dd;
#pragma unroll
    for (int k = 0; k < 4; ++k) dd.u[k] = pd[k];
    *(u16x8*)(PP + (size_t)(i0 + rr) * NROWS + j0 + seg * 8) = dd.v;
  }
}

// One full iteration per launch: coef from fully-accumulated Zprev (int64
// fixed-point, order-independent => deterministic), 128x128 symmetric tile
// partials accumulated into Zacc via int64 atomics. Diagonal blocks zero
// Zzero for use two iterations later. Row pass reads the tile from the
// registers it was loaded into; LDS tile serves only the transposed pass.
__global__ __launch_bounds__(256) void ppmv_atomic(
    const unsigned short* __restrict__ PP,
    const float* __restrict__ unary,
    const long long* __restrict__ Zprev,     // null on iteration 1
    const float* __restrict__ coef0,
    unsigned long long* __restrict__ Zacc,
    unsigned long long* __restrict__ Zzero) { // null on last iteration
  int bi, bj;
  tril64_decode(blockIdx.x, bi, bj);
  const int i0 = bi * 128, j0 = bj * 128;
  const int t = threadIdx.x;

  __shared__ __align__(16) unsigned short tile[128][132];  // 33792 B
  __shared__ float cj[128], ci[128];
  __shared__ float Tw[8][128];

  // issue PP tile loads into registers first (L3/HBM latency overlaps rest)
  const int r = t >> 1, h = (t & 1) * 64;
  u16x8 tv[8];
  {
    const unsigned short* src = PP + (size_t)(i0 + r) * NROWS + j0 + h;
#pragma unroll
    for (int q = 0; q < 8; ++q) tv[q] = *(const u16x8*)(src + q * 8);
  }
  // zero duty: diagonal band zeroes its 128 rows of the buffer accumulated
  // two iterations from now (untouched by anyone this iteration)
  if (bi == bj && Zzero != nullptr && t < 128) Zzero[i0 + t] = 0ull;
  // coef for this thread's assigned row
  {
    int myrow = (t < 128) ? (j0 + t) : (i0 + (t - 128));
    float c;
    if (Zprev) {
      float lg = unary[myrow] + (float)Zprev[myrow] * EINV;
      c = 1.f - 2.f / (1.f + __expf(-lg));
    } else {
      c = coef0[myrow];
    }
    if (t < 128) cj[t] = c;
    else ci[t - 128] = c;
  }
#pragma unroll
  for (int q = 0; q < 8; ++q) *(u16x8*)&tile[r][h + q * 8] = tv[q];
  __syncthreads();
  // row sums (D): matrix data straight from tv registers; coefs from LDS
  {
    float a = 0.f;
#pragma unroll
    for (int q = 0; q < 8; ++q) {
      u16x8 v = tv[q];
      float4 c0 = *(const float4*)&cj[h + q * 8];
      float4 c1 = *(const float4*)&cj[h + q * 8 + 4];
      a += bf2f(v[0]) * c0.x + bf2f(v[1]) * c0.y + bf2f(v[2]) * c0.z + bf2f(v[3]) * c0.w;
      a += bf2f(v[4]) * c1.x + bf2f(v[5]) * c1.y + bf2f(v[6]) * c1.z + bf2f(v[7]) * c1.w;
    }
    a += __shfl_xor(a, 1);
    if ((t & 1) == 0)
      atomicAdd(&Zacc[i0 + r], (unsigned long long)(long long)llrintf(a * ESCALE));
  }
  // col sums (T): thread owns 4 cols x 16 rows (ushort4 LDS reads)
  {
    const int c4 = (t & 31) * 4, rg = t >> 5;
    float a0 = 0.f, a1 = 0.f, a2 = 0.f, a3 = 0.f;
#pragma unroll
    for (int k = 0; k < 16; ++k) {
      int row = rg * 16 + k;
      ushort4 v = *(const ushort4*)&tile[row][c4];
      float s = ci[row];
      a0 += bf2f(v.x) * s; a1 += bf2f(v.y) * s;
      a2 += bf2f(v.z) * s; a3 += bf2f(v.w) * s;
    }
    Tw[rg][c4] = a0; Tw[rg][c4 + 1] = a1;
    Tw[rg][c4 + 2] = a2; Tw[rg][c4 + 3] = a3;
  }
  __syncthreads();
  if (t < 128 && bi != bj) {
    float s = ((Tw[0][t] + Tw[1][t]) + (Tw[2][t] + Tw[3][t])) +
              ((Tw[4][t] + Tw[5][t]) + (Tw[6][t] + Tw[7][t]));
    atomicAdd(&Zacc[j0 + t], (unsigned long long)(long long)llrintf(s * ESCALE));
  }
}

// final: lg = unary + Zfinal*EINV -> out
__global__ __launch_bounds__(256) void final_out(const long long* __restrict__ Z,
                                                 const float* __restrict__ unary,
                                                 float* __restrict__ out) {
  int row = blockIdx.x * 256 + threadIdx.x;
  out[row] = unary[row] + (float)Z[row] * EINV;
}

extern "C" void kernel_launch(void* const* d_in, const int* in_sizes, int n_in,
                              void* d_out, int out_size, void* d_ws, size_t ws_size,
                              hipStream_t stream) {
  const float* x   = (const float*)d_in[0];
  const float* W   = (const float*)d_in[1];
  const float* W1  = (const float*)d_in[2];
  const float* g1  = (const float*)d_in[4];
  const float* be1 = (const float*)d_in[5];
  const float* W2  = (const float*)d_in[6];
  const float* g2  = (const float*)d_in[8];
  const float* be2 = (const float*)d_in[9];
  const float* fcw = (const float*)d_in[10];
  const float* fcb = (const float*)d_in[11];
  float* out = (float*)d_out;

  char* ws = (char*)d_ws;
  unsigned short* hraw = (unsigned short*)(ws + 0);          // 8 MB (dead after bn_apply)
  unsigned short* fraw = (unsigned short*)(ws + 8388608);    // 4 MB
  float* pS1   = (float*)(ws + 12582912);                    // 256 KB
  float* pQ1   = (float*)(ws + 12845056);                    // 256 KB
  float* pS2   = (float*)(ws + 13107200);                    // 128 KB
  float* pQ2   = (float*)(ws + 13238272);                    // 128 KB
  float2* ab1  = (float2*)(ws + 13369344);                   // 4 KB
  float2* ab2  = (float2*)(ws + 13373440);                   // 2 KB
  unsigned short* fnorm = (unsigned short*)(ws + 13375488);  // 4 MB
  float* unary = (float*)(ws + 17569792);
  float* coefA = (float*)(ws + 17602560);
  unsigned short* hb  = (unsigned short*)(ws + 17668096);    // 8 MB
  unsigned short* xb  = (unsigned short*)(ws + 26056704);    // 2 MB
  unsigned short* w1b = (unsigned short*)(ws + 28153856);    // 128 KB
  unsigned short* w2b = (unsigned short*)(ws + 28284928);    // 256 KB
  unsigned short* PP  = (unsigned short*)(ws + 28547072);    // 128 MB -> 162764800
  unsigned long long* Z0 = (unsigned long long*)(ws + 162764800);  // 64 KB
  unsigned long long* Z1 = (unsigned long long*)(ws + 162830336);  // 64 KB
  unsigned long long* Z2 = (unsigned long long*)(ws + 162895872);  // 64 KB
  if (ws_size < (size_t)162961408) return;
  unsigned long long* Z[3] = {Z0, Z1, Z2};

  // casts (one kernel; also zeroes Z0 for iteration 1)
  cast3<<<608, 256, 0, stream>>>(x, W1, W2, xb, w1b, w2b, Z0);
  // layer 1: hraw = x @ W1^T (bf16 out + fused col stats); BN; leaky -> hb
  gemm_bt_mfma_stats<<<dim3(128, 8), 256, 0, stream>>>(xb, w1b, hraw, pS1, pQ1, 512, 128);
  bn_finalize<<<2, 256, 0, stream>>>(pS1, pQ1, g1, be1, ab1, 512);
  bn_apply<<<2048, 256, 0, stream>>>(hraw, ab1, hb, 511);
  // layer 2: fraw = hb @ W2^T (bf16 out + fused col stats); BN+rowfn fused
  gemm_bt_mfma_stats<<<dim3(128, 4), 256, 0, stream>>>(hb, w2b, fraw, pS2, pQ2, 256, 512);
  bn_finalize<<<1, 256, 0, stream>>>(pS2, pQ2, g2, be2, ab2, 256);
  bn_rowfn<<<2048, 256, 0, stream>>>(fraw, ab2, fcw, fcb, fnorm, unary, coefA);
  // PP upper triangle (W prefetched into regs, latency under MFMA K-loop)
  ppbuild_sym<<<8256, 256, 0, stream>>>(fnorm, W, PP);
  // 10 iterations, ONE kernel each (int64 fixed-point atomics: deterministic;
  // no per-iter reduce kernel, no grid.sync (~125 us/sync, round 8), no
  // redundant fp32 fold (65x fan-in, round 11))
  for (int it = 1; it <= NITER; ++it) {
    const long long* zp = (it == 1) ? nullptr : (const long long*)Z[(it + 1) % 3];
    unsigned long long* za = Z[(it - 1) % 3];
    unsigned long long* zz = (it < NITER) ? Z[it % 3] : nullptr;
    ppmv_atomic<<<2080, 256, 0, stream>>>(PP, unary, zp, coefA, za, zz);
  }
  final_out<<<32, 256, 0, stream>>>((const long long*)Z[(NITER - 1) % 3], unary, out);
}